// Round 10
// baseline (93.003 us; speedup 1.0000x reference)
//
#include <hip/hip_runtime.h>
#include <hip/hip_bf16.h>
#include <stdint.h>

typedef __attribute__((ext_vector_type(8))) short bf8;   // 8 bf16 (4 VGPR)
typedef __attribute__((ext_vector_type(4))) short bf4;
typedef __attribute__((ext_vector_type(2))) short bf2;
typedef __attribute__((ext_vector_type(4))) float f32x4;

__device__ inline short f2bf(float f) {
  union { __hip_bfloat16 h; short s; } u;
  u.h = __float2bfloat16(f);
  return u.s;
}
__device__ inline float bf2f(short s) {
  union { short s; __hip_bfloat16 h; } u;
  u.s = s;
  return __bfloat162float(u.h);
}

__device__ inline f32x4 mfma16(bf8 a, bf8 b, f32x4 c) {
  return __builtin_amdgcn_mfma_f32_16x16x32_bf16(a, b, c, 0, 0, 0);
}

// ---------------------------------------------------------------- mega kernel 1
// 1408 blocks. Virtual-id interleave: vid = (bid%11)*128 + bid/11 spreads the
// long kv2 (32-iter) and qproj (16-iter) blocks evenly across CU slots so no
// CU stacks multiple long jobs (round-9 lesson: dispatch-order clustering).
//  vid <64   : kv2   gemm K=1024 (4m x 16n)  -> bf16 + bias
//  vid <192  : qproj gemm K=512  (16m x 8n)  -> bf16 (bias+0.125*log2e scale)
//              (+ x->cat bf16 copy on n0==0 blocks)
//  vid <1216 : kv1   gemm K=256  (64m x 16n) -> bf16 + bias
//  else      : wT[512][1536] = transpose(wproj) bf16 (192 blocks)
__global__ __launch_bounds__(256) void mega1_k(
    const float* __restrict__ x, const float* __restrict__ fore,
    const float* __restrict__ post,
    const float* __restrict__ wq, const float* __restrict__ bq,
    const float* __restrict__ wkv1, const float* __restrict__ bkv1,
    const float* __restrict__ wkv2, const float* __restrict__ bkv2,
    const float* __restrict__ wproj,
    short* __restrict__ qb, short* __restrict__ kv1, short* __restrict__ kv2,
    short* __restrict__ cat, short* __restrict__ wT)
{
  __shared__ __align__(16) short a_lds[2][128 * 40];
  __shared__ __align__(16) short b_lds[2][64 * 40];
  const int bid = blockIdx.x, tid = threadIdx.x;
  const int vid = (bid % 11) * 128 + (bid / 11);   // 1408 = 11*128, bijective

  if (vid >= 1216) {                     // ---- wproj transpose
    float (*tl)[65] = reinterpret_cast<float(*)[65]>(&a_lds[0][0]);
    int tb = vid - 1216;                 // 0..191
    int kt = tb % 24, nt = tb / 24;
    int k0 = kt * 64, n0 = nt * 64;
    int kr = tid >> 2, c4 = tid & 3;
#pragma unroll
    for (int i = 0; i < 4; ++i) {
      int cc = c4 + i * 4;
      float4 v = *(const float4*)&wproj[(size_t)(k0 + kr) * 512 + n0 + cc * 4];
      tl[kr][cc * 4 + 0] = v.x; tl[kr][cc * 4 + 1] = v.y;
      tl[kr][cc * 4 + 2] = v.z; tl[kr][cc * 4 + 3] = v.w;
    }
    __syncthreads();
    int nr = tid >> 2, p = tid & 3;
#pragma unroll
    for (int i = 0; i < 2; ++i) {
      int kk = p * 16 + i * 8;
      bf8 o;
#pragma unroll
      for (int j = 0; j < 8; ++j) o[j] = f2bf(tl[kk + j][nr]);
      *(bf8*)&wT[(size_t)(n0 + nr) * 1536 + k0 + kk] = o;
    }
    return;
  }

  const float *A, *W, *bias;
  short* out;
  int N, lda, ldo, m0, n0, K;
  float osc = 1.f;
  bool wcat = false;
  if (vid < 64) {            // kv2: M=512 N=1024 K=1024
    A = post; W = wkv2; bias = bkv2; out = kv2;
    N = 1024; lda = 1024; ldo = 1024; K = 1024;
    m0 = (vid >> 4) * 128; n0 = (vid & 15) * 64;
  } else if (vid < 192) {    // qproj: M=2048 N=512 K=512
    int j = vid - 64;
    A = x; W = wq; bias = bq; out = qb;
    N = 512; lda = 512; ldo = 512; K = 512;
    m0 = (j >> 3) * 128; n0 = (j & 7) * 64;
    osc = 0.125f * 1.44269504088896f;
    wcat = (j & 7) == 0;
  } else {                   // kv1: M=8192 N=1024 K=256
    int j = vid - 192;
    A = fore; W = wkv1; bias = bkv1; out = kv1;
    N = 1024; lda = 256; ldo = 1024; K = 256;
    m0 = (j >> 4) * 128; n0 = (j & 15) * 64;
  }

  const int w = tid >> 6, lane = tid & 63, g = lane >> 4, lr = lane & 15;
  const int wrow = w & 1, wcol = w >> 1;

  f32x4 z = {0.f, 0.f, 0.f, 0.f};
  f32x4 acc[4][2];
#pragma unroll
  for (int mi = 0; mi < 4; ++mi)
#pragma unroll
    for (int ni = 0; ni < 2; ++ni) acc[mi][ni] = z;

  const int arow = tid >> 3, ac4 = tid & 7;
  const int bcol = tid & 63, bj4 = tid >> 6;

  float4 ra[4], rna[4];
  float rw[8], rnw[8];

  auto LOADA = [&](int kg, float4* af, float* wg) {
#pragma unroll
    for (int i = 0; i < 4; ++i)
      af[i] = *(const float4*)&A[(size_t)(m0 + arow + 32 * i) * lda + kg + ac4 * 4];
#pragma unroll
    for (int j = 0; j < 8; ++j)
      wg[j] = W[(size_t)(kg + bj4 * 8 + j) * N + n0 + bcol];
  };
  auto STAGE = [&](int b, const float4* af, const float* wg, int kg) {
#pragma unroll
    for (int i = 0; i < 4; ++i) {
      int rr = arow + 32 * i;
      int s = (ac4 >> 1) ^ (rr & 3);
      bf4 o;
      o[0] = f2bf(af[i].x); o[1] = f2bf(af[i].y);
      o[2] = f2bf(af[i].z); o[3] = f2bf(af[i].w);
      *(bf4*)&a_lds[b][rr * 40 + s * 8 + (ac4 & 1) * 4] = o;
      if (wcat)
        *(bf4*)&cat[(size_t)(m0 + rr) * 1536 + kg + ac4 * 4] = o;
    }
    int s = bj4 ^ (bcol & 3);
    bf8 o;
#pragma unroll
    for (int j = 0; j < 8; ++j) o[j] = f2bf(wg[j]);
    *(bf8*)&b_lds[b][bcol * 40 + s * 8] = o;
  };

  const int nit = K >> 5;
  LOADA(0, ra, rw);
  STAGE(0, ra, rw, 0);
  LOADA(32, rna, rnw);
  __syncthreads();

  for (int it = 0; it < nit; ++it) {
    if (it + 1 < nit) STAGE((it + 1) & 1, rna, rnw, (it + 1) * 32);
    if (it + 2 < nit) LOADA((it + 2) * 32, rna, rnw);

    const int b = it & 1;
    bf8 afr[4], bfr[2];
#pragma unroll
    for (int mi = 0; mi < 4; ++mi) {
      int row = wrow * 64 + mi * 16 + lr;
      afr[mi] = *(const bf8*)&a_lds[b][row * 40 + ((g ^ (row & 3)) << 3)];
    }
#pragma unroll
    for (int ni = 0; ni < 2; ++ni) {
      int col = wcol * 32 + ni * 16 + lr;
      bfr[ni] = *(const bf8*)&b_lds[b][col * 40 + ((g ^ (col & 3)) << 3)];
    }
#pragma unroll
    for (int mi = 0; mi < 4; ++mi)
#pragma unroll
      for (int ni = 0; ni < 2; ++ni)
        acc[mi][ni] = mfma16(afr[mi], bfr[ni], acc[mi][ni]);
    __syncthreads();
  }

#pragma unroll
  for (int ni = 0; ni < 2; ++ni) {
    int col = n0 + wcol * 32 + ni * 16 + lr;
    float bv = bias[col];
#pragma unroll
    for (int mi = 0; mi < 4; ++mi) {
      int rowb = m0 + wrow * 64 + mi * 16 + g * 4;
#pragma unroll
      for (int r = 0; r < 4; ++r)
        out[(size_t)(rowb + r) * ldo + col] = f2bf((acc[mi][ni][r] + bv) * osc);
    }
  }
}

// ---------------------------------------------------------------- attention
// bid<1024: attn1 (kv1, chunk 512, nsplit 8) -> bf16 O partials + f32 l partials
// bid>=1024: attn2 (kv2, full 256, nsplit 1) -> normalized, direct to cat
// Decode keeps kv-chunk sharers bid%8-aligned (same XCD L2).
__global__ __launch_bounds__(256) void attn_k(
    const short* __restrict__ q,
    const short* __restrict__ kv1, const short* __restrict__ kv2,
    short* __restrict__ o1, float* __restrict__ l1,
    short* __restrict__ cat)
{
  __shared__ __align__(16) short k_lds[64 * 64];   // [lc][d] XOR-swizzled octets
  __shared__ __align__(16) short v_lds[64 * 72];   // [d][lc-permuted]
  const int tid = threadIdx.x;
  const int w = tid >> 6, lane = tid & 63, g = lane >> 4, lr = lane & 15;

  const int bid = blockIdx.x;
  const short* kvsrc;
  int qt, h, bb, split, chunk, Lc;
  bool direct;
  if (bid < 1024) {
    qt = bid >> 7; int j = bid & 127;
    h = j & 7; int zz = j >> 3;
    bb = zz >> 3; split = zz & 7;
    kvsrc = kv1; chunk = 512; Lc = 4096; direct = false;
  } else {
    int j2 = bid - 1024;
    qt = j2 >> 4; int r = j2 & 15;
    h = r & 7; bb = r >> 3; split = 0;
    kvsrc = kv2; chunk = 256; Lc = 256; direct = true;
  }

  // Q: 32 rows per wave, 2 sets of 16 (B-operand fragments)
  const int qbase = bb * 1024 + qt * 128 + w * 32;
  bf8 qfA[2], qfB[2];
#pragma unroll
  for (int s2 = 0; s2 < 2; ++s2) {
    const short* qp = &q[(size_t)(qbase + s2 * 16 + lr) * 512 + h * 64];
    qfA[s2] = *(const bf8*)&qp[g * 8];
    qfB[s2] = *(const bf8*)&qp[32 + g * 8];
  }

  const f32x4 z = {0.f, 0.f, 0.f, 0.f};
  f32x4 oaccT[2][4];   // [set][dt] : O^T rows d=16dt+4g+r, col q=lr
#pragma unroll
  for (int s2 = 0; s2 < 2; ++s2)
#pragma unroll
    for (int i = 0; i < 4; ++i) oaccT[s2][i] = z;
  float lsum_l[2] = {0.f, 0.f};

  const short* kvb = kvsrc + (size_t)bb * Lc * 1024 + (size_t)split * chunk * 1024;

  const int krow = tid >> 2, ksl = tid & 3;
  const short* kgp = kvb + (size_t)krow * 1024 + h * 64;
  const int vi = tid & 31, vj = tid >> 5;
  const short* vgp = kvb + (size_t)(2 * vi) * 1024 + 512 + h * 64 + vj * 8;
  const int lc0 = 2 * vi;
  const int vpos = (lc0 & 32) + ((lc0 & 12) << 1) + ((lc0 & 16) >> 2) + (lc0 & 3);

  bf8 k0c, k1c, v0c, v1c;
  k0c = *(const bf8*)(kgp + ksl * 8);
  k1c = *(const bf8*)(kgp + (ksl + 4) * 8);
  v0c = *(const bf8*)vgp;
  v1c = *(const bf8*)(vgp + 1024);

  const int nit = chunk >> 6;
  for (int it = 0; it < nit; ++it) {
    __syncthreads();
    *(bf8*)&k_lds[krow * 64 + ((ksl ^ (krow & 7)) << 3)] = k0c;
    *(bf8*)&k_lds[krow * 64 + (((ksl + 4) ^ (krow & 7)) << 3)] = k1c;
#pragma unroll
    for (int jj = 0; jj < 8; ++jj) {
      int d = vj * 8 + jj;
      bf2 pr; pr[0] = v0c[jj]; pr[1] = v1c[jj];
      *(bf2*)&v_lds[d * 72 + vpos] = pr;
    }
    __syncthreads();
    if (it + 1 < nit) {
      size_t off = (size_t)64 * 1024 * (it + 1);
      k0c = *(const bf8*)(kgp + off + ksl * 8);
      k1c = *(const bf8*)(kgp + off + (ksl + 4) * 8);
      v0c = *(const bf8*)(vgp + off);
      v1c = *(const bf8*)(vgp + off + 1024);
    }

    // S^T = (K Q^T) ; q prescaled by 0.125*log2e so p = exp2(s')
    f32x4 sv[2][4];
#pragma unroll
    for (int t = 0; t < 4; ++t) {
      int lc = t * 16 + lr;
      bf8 kf0 = *(const bf8*)&k_lds[lc * 64 + ((g ^ (lc & 7)) << 3)];
      bf8 kf1 = *(const bf8*)&k_lds[lc * 64 + (((4 + g) ^ (lc & 7)) << 3)];
#pragma unroll
      for (int s2 = 0; s2 < 2; ++s2) {
        sv[s2][t] = mfma16(kf0, qfA[s2], z);
        sv[s2][t] = mfma16(kf1, qfB[s2], sv[s2][t]);
      }
    }

    // p = exp2(s'); pack B-frags in-lane
    bf8 pb[2][2];
#pragma unroll
    for (int s2 = 0; s2 < 2; ++s2) {
      float acc_l = 0.f;
#pragma unroll
      for (int t = 0; t < 4; ++t) {
        float p0 = exp2f(sv[s2][t][0]);
        float p1 = exp2f(sv[s2][t][1]);
        float p2 = exp2f(sv[s2][t][2]);
        float p3 = exp2f(sv[s2][t][3]);
        acc_l += (p0 + p1) + (p2 + p3);
        int c = t >> 1, hb = (t & 1) * 4;
        pb[s2][c][hb + 0] = f2bf(p0);
        pb[s2][c][hb + 1] = f2bf(p1);
        pb[s2][c][hb + 2] = f2bf(p2);
        pb[s2][c][hb + 3] = f2bf(p3);
      }
      lsum_l[s2] += acc_l;
    }

    // O^T += V^T P
#pragma unroll
    for (int dt = 0; dt < 4; ++dt) {
      int d = dt * 16 + lr;
      bf8 vf0 = *(const bf8*)&v_lds[d * 72 + 8 * g];
      bf8 vf1 = *(const bf8*)&v_lds[d * 72 + 32 + 8 * g];
      oaccT[0][dt] = mfma16(vf0, pb[0][0], oaccT[0][dt]);
      oaccT[0][dt] = mfma16(vf1, pb[0][1], oaccT[0][dt]);
      oaccT[1][dt] = mfma16(vf0, pb[1][0], oaccT[1][dt]);
      oaccT[1][dt] = mfma16(vf1, pb[1][1], oaccT[1][dt]);
    }
  }

  if (direct) {
    // normalize in-register, write straight to cat (column block 1024..1535)
#pragma unroll
    for (int s2 = 0; s2 < 2; ++s2) {
      float t = lsum_l[s2];
      t += __shfl_xor(t, 16);
      t += __shfl_xor(t, 32);
      float rle = 1.f / t;
      int qrow = qbase + s2 * 16 + lr;
#pragma unroll
      for (int dt = 0; dt < 4; ++dt) {
        bf4 o4;
#pragma unroll
        for (int r = 0; r < 4; ++r) o4[r] = f2bf(oaccT[s2][dt][r] * rle);
        *(bf4*)&cat[(size_t)qrow * 1536 + 1024 + h * 64 + dt * 16 + 4 * g] = o4;
      }
    }
    return;
  }

  // region1 epilogue: bf16 unnormalized O partials + f32 exp-sum partials
#pragma unroll
  for (int s2 = 0; s2 < 2; ++s2) {
    int prow = (bb * 8 + h) * 1024 + qt * 128 + w * 32 + s2 * 16 + lr;
    short* ob = o1 + ((size_t)split * 16384 + prow) * 64;
#pragma unroll
    for (int dt = 0; dt < 4; ++dt) {
      bf4 o4;
#pragma unroll
      for (int r = 0; r < 4; ++r) o4[r] = f2bf(oaccT[s2][dt][r]);
      *(bf4*)&ob[dt * 16 + 4 * g] = o4;
    }
    float t = lsum_l[s2];
    t += __shfl_xor(t, 16);
    t += __shfl_xor(t, 32);
    if (g == 0) l1[(size_t)split * 16384 + prow] = t;
  }
}

// ---------------------------------------------------------------- combine region1 partials
// 512 blocks; 8 threads per row (bf8 of d), 32 rows/block, 8 splits
__global__ __launch_bounds__(256) void comb_k(
    const short* __restrict__ o1, const float* __restrict__ l1,
    short* __restrict__ cat)
{
  int row = blockIdx.x * 32 + (threadIdx.x >> 3);
  int d8 = (threadIdx.x & 7) * 8;
  float l = 0.f;
#pragma unroll
  for (int s = 0; s < 8; ++s) l += l1[(size_t)s * 16384 + row];
  float acc[8] = {};
#pragma unroll
  for (int s = 0; s < 8; ++s) {
    bf8 v = *(const bf8*)&o1[((size_t)s * 16384 + row) * 64 + d8];
#pragma unroll
    for (int j = 0; j < 8; ++j) acc[j] += bf2f(v[j]);
  }
  float rle = 1.f / l;
  bf8 o;
#pragma unroll
  for (int j = 0; j < 8; ++j) o[j] = f2bf(acc[j] * rle);
  int bb = row >> 13, h = (row >> 10) & 7, qr = row & 1023;
  *(bf8*)&cat[(size_t)(bb * 1024 + qr) * 1536 + 512 + h * 64 + d8] = o;
}

// ---------------------------------------------------------------- GEMM (outproj, dbuf, bf16 W^T)
// C[2048,512] = cat[2048,1536] @ W + bias ; tile 32x64, 512 blocks (2/CU).
// Decode m = id&63, n = id>>6: the 8 same-m blocks are bid%8-aligned (same XCD)
// and share the cat m-slab in that XCD's L2.
__global__ __launch_bounds__(256) void gemmo_k(
    const short* __restrict__ A, const short* __restrict__ wT,
    const float* __restrict__ bias, float* __restrict__ out)
{
  __shared__ __align__(16) short a_lds[2][32 * 40];
  __shared__ __align__(16) short b_lds[2][64 * 40];
  const int tid = threadIdx.x;
  const int w = tid >> 6, lane = tid & 63, g = lane >> 4, lr = lane & 15;
  const int id = blockIdx.x;
  const int m0 = (id & 63) * 32, n0 = (id >> 6) * 64;
  const int K = 1536;

  f32x4 z = {0.f, 0.f, 0.f, 0.f};
  f32x4 acc[2];
  acc[0] = z; acc[1] = z;

  const int arow = tid >> 3, ac4 = tid & 7;     // A: 32 rows x 32 k, bf4/thread
  const int bcol = tid & 63, bj4 = tid >> 6;    // B: 64 cols x 32 k, bf8/thread
  bf4 ra, rna;
  bf8 rb, rnb;

  auto LOADAB = [&](int kg, bf4& ab, bf8& bb) {
    ab = *(const bf4*)&A[(size_t)(m0 + arow) * K + kg + ac4 * 4];
    bb = *(const bf8*)&wT[(size_t)(n0 + bcol) * K + kg + bj4 * 8];
  };
  auto STAGE = [&](int b, bf4 ab, bf8 bb) {
    int s = (ac4 >> 1) ^ (arow & 3);
    *(bf4*)&a_lds[b][arow * 40 + s * 8 + (ac4 & 1) * 4] = ab;
    *(bf8*)&b_lds[b][bcol * 40 + ((bj4 ^ (bcol & 3)) << 3)] = bb;
  };

  const int nit = K >> 5;
  LOADAB(0, ra, rb);
  STAGE(0, ra, rb);
  LOADAB(32, rna, rnb);
  __syncthreads();

  for (int it = 0; it < nit; ++it) {
    if (it + 1 < nit) STAGE((it + 1) & 1, rna, rnb);
    if (it + 2 < nit) LOADAB((it + 2) * 32, rna, rnb);

    const int b = it & 1;
    bf8 afr[2], bfr;
#pragma unroll
    for (int mi = 0; mi < 2; ++mi) {
      int row = mi * 16 + lr;
      afr[mi] = *(const bf8*)&a_lds[b][row * 40 + ((g ^ (row & 3)) << 3)];
    }
    {
      int col = w * 16 + lr;
      bfr = *(const bf8*)&b_lds[b][col * 40 + ((g ^ (col & 3)) << 3)];
    }
    acc[0] = mfma16(afr[0], bfr, acc[0]);
    acc[1] = mfma16(afr[1], bfr, acc[1]);
    __syncthreads();
  }

  {
    int col = n0 + w * 16 + lr;
    float bv = bias[col];
#pragma unroll
    for (int mi = 0; mi < 2; ++mi) {
      int rowb = m0 + mi * 16 + g * 4;
#pragma unroll
      for (int r = 0; r < 4; ++r)
        out[(size_t)(rowb + r) * 512 + col] = acc[mi][r] + bv;
    }
  }
}

// ---------------------------------------------------------------- launch
extern "C" void kernel_launch(void* const* d_in, const int* in_sizes, int n_in,
                              void* d_out, int out_size, void* d_ws, size_t ws_size,
                              hipStream_t stream) {
  const float* x     = (const float*)d_in[0];
  const float* fore  = (const float*)d_in[1];
  const float* post  = (const float*)d_in[2];
  const float* wq    = (const float*)d_in[3];
  const float* bq    = (const float*)d_in[4];
  const float* wkv1  = (const float*)d_in[5];
  const float* bkv1  = (const float*)d_in[6];
  const float* wkv2  = (const float*)d_in[7];
  const float* bkv2  = (const float*)d_in[8];
  const float* wproj = (const float*)d_in[9];
  const float* bproj = (const float*)d_in[10];

  char* ws = (char*)d_ws;
  short* qb  = (short*)ws;                          // 2048*512  bf16 =  2 MB
  short* kv1 = (short*)(ws + (2ull << 20));         // 8192*1024 bf16 = 16 MB
  short* kv2 = (short*)(ws + (18ull << 20));        // 512*1024  bf16 =  1 MB
  short* cat = (short*)(ws + (19ull << 20));        // 2048*1536 bf16 =  6 MB
  short* o1  = (short*)(ws + (25ull << 20));        // 8*16384*64 bf16 = 16 MB
  float* l1  = (float*)(ws + (41ull << 20));        // 8*16384 f32 = 512 KB
  short* wT  = (short*)(ws + (42ull << 20));        // 512*1536 bf16 = 1.5 MB

  mega1_k<<<1408, 256, 0, stream>>>(x, fore, post, wq, bq, wkv1, bkv1,
                                    wkv2, bkv2, wproj, qb, kv1, kv2, cat, wT);
  attn_k<<<1152, 256, 0, stream>>>(qb, kv1, kv2, o1, l1, cat);
  comb_k<<<512, 256, 0, stream>>>(o1, l1, cat);
  gemmo_k<<<512, 256, 0, stream>>>(cat, wT, bproj, (float*)d_out);
}

// Round 11
// 85.771 us; speedup vs baseline: 1.0843x; 1.0843x over previous
//
#include <hip/hip_runtime.h>
#include <hip/hip_bf16.h>
#include <stdint.h>

typedef __attribute__((ext_vector_type(8))) short bf8;   // 8 bf16 (4 VGPR)
typedef __attribute__((ext_vector_type(4))) short bf4;
typedef __attribute__((ext_vector_type(2))) short bf2;
typedef __attribute__((ext_vector_type(4))) float f32x4;

__device__ inline short f2bf(float f) {
  union { __hip_bfloat16 h; short s; } u;
  u.h = __float2bfloat16(f);
  return u.s;
}
__device__ inline float bf2f(short s) {
  union { short s; __hip_bfloat16 h; } u;
  u.s = s;
  return __bfloat162float(u.h);
}

__device__ inline f32x4 mfma16(bf8 a, bf8 b, f32x4 c) {
  return __builtin_amdgcn_mfma_f32_16x16x32_bf16(a, b, c, 0, 0, 0);
}

// ---------------------------------------------------------------- cvt + transpose pre-pass
// bid < 576 : 64x64 weight transpose tiles f32[K][N] -> bf16 WT[N][K]
//   0..63   wq (512x512) ; 64..127 wkv1 (256x1024) ; 128..383 wkv2 (1024x1024)
//   384..575 wproj (1536x512)
// bid >= 576: elementwise f32->bf16 (x -> xb AND cat[:,0:512]; fore -> fb; post -> pb)
__global__ __launch_bounds__(256) void cvtw_k(
    const float* __restrict__ x, const float* __restrict__ fore,
    const float* __restrict__ post,
    const float* __restrict__ wq, const float* __restrict__ wkv1,
    const float* __restrict__ wkv2, const float* __restrict__ wproj,
    short* __restrict__ xb, short* __restrict__ fb, short* __restrict__ pb,
    short* __restrict__ cat,
    short* __restrict__ wqT, short* __restrict__ wkv1T,
    short* __restrict__ wkv2T, short* __restrict__ wT)
{
  __shared__ float tl[64][65];
  const int bid = blockIdx.x, tid = threadIdx.x;
  if (bid < 576) {
    const float* Win; short* WT; int K, N, kt, nt;
    if (bid < 64)       { Win = wq;    WT = wqT;   K = 512;  N = 512;  kt = bid >> 3;  nt = bid & 7; }
    else if (bid < 128) { int j = bid - 64;  Win = wkv1;  WT = wkv1T; K = 256;  N = 1024; kt = j >> 4; nt = j & 15; }
    else if (bid < 384) { int j = bid - 128; Win = wkv2;  WT = wkv2T; K = 1024; N = 1024; kt = j >> 4; nt = j & 15; }
    else                { int j = bid - 384; Win = wproj; WT = wT;    K = 1536; N = 512;  kt = j % 24; nt = j / 24; }
    const int k0 = kt * 64, n0 = nt * 64;
    const int kr = tid >> 2, c4 = tid & 3;
#pragma unroll
    for (int i = 0; i < 4; ++i) {
      int cc = c4 + i * 4;
      float4 v = *(const float4*)&Win[(size_t)(k0 + kr) * N + n0 + cc * 4];
      tl[kr][cc * 4 + 0] = v.x; tl[kr][cc * 4 + 1] = v.y;
      tl[kr][cc * 4 + 2] = v.z; tl[kr][cc * 4 + 3] = v.w;
    }
    __syncthreads();
    const int nr = tid >> 2, p = tid & 3;
#pragma unroll
    for (int i = 0; i < 2; ++i) {
      int kk = p * 16 + i * 8;
      bf8 o;
#pragma unroll
      for (int j = 0; j < 8; ++j) o[j] = f2bf(tl[kk + j][nr]);
      *(bf8*)&WT[(size_t)(n0 + nr) * K + k0 + kk] = o;
    }
    return;
  }
  // elementwise: 896 blocks x 1024 float4
  int e0 = (bid - 576) * 1024 + tid;
#pragma unroll
  for (int i = 0; i < 4; ++i) {
    int q4 = e0 + 256 * i;
    float4 v;
    bf4 o;
    if (q4 < 262144) {
      v = ((const float4*)x)[q4];
      o[0] = f2bf(v.x); o[1] = f2bf(v.y); o[2] = f2bf(v.z); o[3] = f2bf(v.w);
      ((bf4*)xb)[q4] = o;
      int row = q4 >> 7, col = (q4 & 127) * 4;
      *(bf4*)&cat[(size_t)row * 1536 + col] = o;
    } else if (q4 < 786432) {
      int j = q4 - 262144;
      v = ((const float4*)fore)[j];
      o[0] = f2bf(v.x); o[1] = f2bf(v.y); o[2] = f2bf(v.z); o[3] = f2bf(v.w);
      ((bf4*)fb)[j] = o;
    } else {
      int j = q4 - 786432;
      v = ((const float4*)post)[j];
      o[0] = f2bf(v.x); o[1] = f2bf(v.y); o[2] = f2bf(v.z); o[3] = f2bf(v.w);
      ((bf4*)pb)[j] = o;
    }
  }
}

// ---------------------------------------------------------------- mega GEMM (pure bf16)
// 1216 blocks, natural round-9 order (long jobs first), no split-K:
//  bid <64   : kv2   K=1024 (4m x 16n)  A=pb  WT=wkv2T -> kv2 + bias
//  bid <192  : qproj K=512  (16m x 8n)  A=xb  WT=wqT   -> qb (bias, *0.125*log2e)
//  else      : kv1   K=256  (64m x 16n) A=fb  WT=wkv1T -> kv1 + bias
// Staging is pure bf8 copy (no cvt): ~40 VALU/iter vs ~200 in the f32 path.
__global__ __launch_bounds__(256) void mega1_k(
    const short* __restrict__ xb, const short* __restrict__ fb,
    const short* __restrict__ pb,
    const short* __restrict__ wqT, const short* __restrict__ wkv1T,
    const short* __restrict__ wkv2T,
    const float* __restrict__ bq, const float* __restrict__ bkv1,
    const float* __restrict__ bkv2,
    short* __restrict__ qb, short* __restrict__ kv1, short* __restrict__ kv2)
{
  __shared__ __align__(16) short a_lds[2][128 * 40];
  __shared__ __align__(16) short b_lds[2][64 * 40];
  const int bid = blockIdx.x, tid = threadIdx.x;

  const short *A, *WT;
  const float* bias;
  short* out;
  int K, N, m0, n0;
  float osc = 1.f;
  if (bid < 64) {            // kv2: M=512 N=1024 K=1024
    A = pb; WT = wkv2T; bias = bkv2; out = kv2;
    K = 1024; N = 1024;
    m0 = (bid >> 4) * 128; n0 = (bid & 15) * 64;
  } else if (bid < 192) {    // qproj: M=2048 N=512 K=512
    int j = bid - 64;
    A = xb; WT = wqT; bias = bq; out = qb;
    K = 512; N = 512;
    m0 = (j >> 3) * 128; n0 = (j & 7) * 64;
    osc = 0.125f * 1.44269504088896f;
  } else {                   // kv1: M=8192 N=1024 K=256
    int j = bid - 192;
    A = fb; WT = wkv1T; bias = bkv1; out = kv1;
    K = 256; N = 1024;
    m0 = (j >> 4) * 128; n0 = (j & 15) * 64;
  }

  const int w = tid >> 6, lane = tid & 63, g = lane >> 4, lr = lane & 15;
  const int wrow = w & 1, wcol = w >> 1;

  f32x4 z = {0.f, 0.f, 0.f, 0.f};
  f32x4 acc[4][2];
#pragma unroll
  for (int mi = 0; mi < 4; ++mi)
#pragma unroll
    for (int ni = 0; ni < 2; ++ni) acc[mi][ni] = z;

  const int arow = tid >> 2, ac8 = tid & 3;     // A: 64 rows x 4 octets (x2 rows)
  const int bcol = tid >> 2, bks = tid & 3;     // B: 64 cols x 4 octets

  bf8 ra[2], rna[2], rb, rnb;

  auto LOADAB = [&](int kg, bf8* a, bf8& b) {
    a[0] = *(const bf8*)&A[(size_t)(m0 + arow) * K + kg + ac8 * 8];
    a[1] = *(const bf8*)&A[(size_t)(m0 + arow + 64) * K + kg + ac8 * 8];
    b = *(const bf8*)&WT[(size_t)(n0 + bcol) * K + kg + bks * 8];
  };
  auto STAGE = [&](int b_, const bf8* a, bf8 b) {
    *(bf8*)&a_lds[b_][arow * 40 + ((ac8 ^ (arow & 3)) << 3)] = a[0];
    int r2 = arow + 64;
    *(bf8*)&a_lds[b_][r2 * 40 + ((ac8 ^ (r2 & 3)) << 3)] = a[1];
    *(bf8*)&b_lds[b_][bcol * 40 + ((bks ^ (bcol & 3)) << 3)] = b;
  };

  const int nit = K >> 5;
  LOADAB(0, ra, rb);
  STAGE(0, ra, rb);
  LOADAB(32, rna, rnb);
  __syncthreads();

  for (int it = 0; it < nit; ++it) {
    if (it + 1 < nit) STAGE((it + 1) & 1, rna, rnb);
    if (it + 2 < nit) LOADAB((it + 2) * 32, rna, rnb);

    const int b = it & 1;
    bf8 afr[4], bfr[2];
#pragma unroll
    for (int mi = 0; mi < 4; ++mi) {
      int row = wrow * 64 + mi * 16 + lr;
      afr[mi] = *(const bf8*)&a_lds[b][row * 40 + ((g ^ (row & 3)) << 3)];
    }
#pragma unroll
    for (int ni = 0; ni < 2; ++ni) {
      int col = wcol * 32 + ni * 16 + lr;
      bfr[ni] = *(const bf8*)&b_lds[b][col * 40 + ((g ^ (col & 3)) << 3)];
    }
#pragma unroll
    for (int mi = 0; mi < 4; ++mi)
#pragma unroll
      for (int ni = 0; ni < 2; ++ni)
        acc[mi][ni] = mfma16(afr[mi], bfr[ni], acc[mi][ni]);
    __syncthreads();
  }

#pragma unroll
  for (int ni = 0; ni < 2; ++ni) {
    int col = n0 + wcol * 32 + ni * 16 + lr;
    float bv = bias[col];
#pragma unroll
    for (int mi = 0; mi < 4; ++mi) {
      int rowb = m0 + wrow * 64 + mi * 16 + g * 4;
#pragma unroll
      for (int r = 0; r < 4; ++r)
        out[(size_t)(rowb + r) * N + col] = f2bf((acc[mi][ni][r] + bv) * osc);
    }
  }
}

// ---------------------------------------------------------------- attention (round-9 verbatim)
// bid<1024: attn1 (kv1, chunk 512, nsplit 8) -> bf16 O partials + f32 l partials
// bid>=1024: attn2 (kv2, full 256, nsplit 1) -> normalized, direct to cat
__global__ __launch_bounds__(256) void attn_k(
    const short* __restrict__ q,
    const short* __restrict__ kv1, const short* __restrict__ kv2,
    short* __restrict__ o1, float* __restrict__ l1,
    short* __restrict__ cat)
{
  __shared__ __align__(16) short k_lds[64 * 64];   // [lc][d] XOR-swizzled octets
  __shared__ __align__(16) short v_lds[64 * 72];   // [d][lc-permuted]
  const int tid = threadIdx.x;
  const int w = tid >> 6, lane = tid & 63, g = lane >> 4, lr = lane & 15;

  const int bid = blockIdx.x;
  const short* kvsrc;
  int qt, h, bb, split, chunk, Lc;
  bool direct;
  if (bid < 1024) {
    qt = bid >> 7; int j = bid & 127;
    h = j & 7; int zz = j >> 3;
    bb = zz >> 3; split = zz & 7;
    kvsrc = kv1; chunk = 512; Lc = 4096; direct = false;
  } else {
    int j2 = bid - 1024;
    qt = j2 >> 4; int r = j2 & 15;
    h = r & 7; bb = r >> 3; split = 0;
    kvsrc = kv2; chunk = 256; Lc = 256; direct = true;
  }

  const int qbase = bb * 1024 + qt * 128 + w * 32;
  bf8 qfA[2], qfB[2];
#pragma unroll
  for (int s2 = 0; s2 < 2; ++s2) {
    const short* qp = &q[(size_t)(qbase + s2 * 16 + lr) * 512 + h * 64];
    qfA[s2] = *(const bf8*)&qp[g * 8];
    qfB[s2] = *(const bf8*)&qp[32 + g * 8];
  }

  const f32x4 z = {0.f, 0.f, 0.f, 0.f};
  f32x4 oaccT[2][4];
#pragma unroll
  for (int s2 = 0; s2 < 2; ++s2)
#pragma unroll
    for (int i = 0; i < 4; ++i) oaccT[s2][i] = z;
  float lsum_l[2] = {0.f, 0.f};

  const short* kvb = kvsrc + (size_t)bb * Lc * 1024 + (size_t)split * chunk * 1024;

  const int krow = tid >> 2, ksl = tid & 3;
  const short* kgp = kvb + (size_t)krow * 1024 + h * 64;
  const int vi = tid & 31, vj = tid >> 5;
  const short* vgp = kvb + (size_t)(2 * vi) * 1024 + 512 + h * 64 + vj * 8;
  const int lc0 = 2 * vi;
  const int vpos = (lc0 & 32) + ((lc0 & 12) << 1) + ((lc0 & 16) >> 2) + (lc0 & 3);

  bf8 k0c, k1c, v0c, v1c;
  k0c = *(const bf8*)(kgp + ksl * 8);
  k1c = *(const bf8*)(kgp + (ksl + 4) * 8);
  v0c = *(const bf8*)vgp;
  v1c = *(const bf8*)(vgp + 1024);

  const int nit = chunk >> 6;
  for (int it = 0; it < nit; ++it) {
    __syncthreads();
    *(bf8*)&k_lds[krow * 64 + ((ksl ^ (krow & 7)) << 3)] = k0c;
    *(bf8*)&k_lds[krow * 64 + (((ksl + 4) ^ (krow & 7)) << 3)] = k1c;
#pragma unroll
    for (int jj = 0; jj < 8; ++jj) {
      int d = vj * 8 + jj;
      bf2 pr; pr[0] = v0c[jj]; pr[1] = v1c[jj];
      *(bf2*)&v_lds[d * 72 + vpos] = pr;
    }
    __syncthreads();
    if (it + 1 < nit) {
      size_t off = (size_t)64 * 1024 * (it + 1);
      k0c = *(const bf8*)(kgp + off + ksl * 8);
      k1c = *(const bf8*)(kgp + off + (ksl + 4) * 8);
      v0c = *(const bf8*)(vgp + off);
      v1c = *(const bf8*)(vgp + off + 1024);
    }

    f32x4 sv[2][4];
#pragma unroll
    for (int t = 0; t < 4; ++t) {
      int lc = t * 16 + lr;
      bf8 kf0 = *(const bf8*)&k_lds[lc * 64 + ((g ^ (lc & 7)) << 3)];
      bf8 kf1 = *(const bf8*)&k_lds[lc * 64 + (((4 + g) ^ (lc & 7)) << 3)];
#pragma unroll
      for (int s2 = 0; s2 < 2; ++s2) {
        sv[s2][t] = mfma16(kf0, qfA[s2], z);
        sv[s2][t] = mfma16(kf1, qfB[s2], sv[s2][t]);
      }
    }

    bf8 pb2[2][2];
#pragma unroll
    for (int s2 = 0; s2 < 2; ++s2) {
      float acc_l = 0.f;
#pragma unroll
      for (int t = 0; t < 4; ++t) {
        float p0 = exp2f(sv[s2][t][0]);
        float p1 = exp2f(sv[s2][t][1]);
        float p2 = exp2f(sv[s2][t][2]);
        float p3 = exp2f(sv[s2][t][3]);
        acc_l += (p0 + p1) + (p2 + p3);
        int c = t >> 1, hb = (t & 1) * 4;
        pb2[s2][c][hb + 0] = f2bf(p0);
        pb2[s2][c][hb + 1] = f2bf(p1);
        pb2[s2][c][hb + 2] = f2bf(p2);
        pb2[s2][c][hb + 3] = f2bf(p3);
      }
      lsum_l[s2] += acc_l;
    }

#pragma unroll
    for (int dt = 0; dt < 4; ++dt) {
      int d = dt * 16 + lr;
      bf8 vf0 = *(const bf8*)&v_lds[d * 72 + 8 * g];
      bf8 vf1 = *(const bf8*)&v_lds[d * 72 + 32 + 8 * g];
      oaccT[0][dt] = mfma16(vf0, pb2[0][0], oaccT[0][dt]);
      oaccT[0][dt] = mfma16(vf1, pb2[0][1], oaccT[0][dt]);
      oaccT[1][dt] = mfma16(vf0, pb2[1][0], oaccT[1][dt]);
      oaccT[1][dt] = mfma16(vf1, pb2[1][1], oaccT[1][dt]);
    }
  }

  if (direct) {
#pragma unroll
    for (int s2 = 0; s2 < 2; ++s2) {
      float t = lsum_l[s2];
      t += __shfl_xor(t, 16);
      t += __shfl_xor(t, 32);
      float rle = 1.f / t;
      int qrow = qbase + s2 * 16 + lr;
#pragma unroll
      for (int dt = 0; dt < 4; ++dt) {
        bf4 o4;
#pragma unroll
        for (int r = 0; r < 4; ++r) o4[r] = f2bf(oaccT[s2][dt][r] * rle);
        *(bf4*)&cat[(size_t)qrow * 1536 + 1024 + h * 64 + dt * 16 + 4 * g] = o4;
      }
    }
    return;
  }

#pragma unroll
  for (int s2 = 0; s2 < 2; ++s2) {
    int prow = (bb * 8 + h) * 1024 + qt * 128 + w * 32 + s2 * 16 + lr;
    short* ob = o1 + ((size_t)split * 16384 + prow) * 64;
#pragma unroll
    for (int dt = 0; dt < 4; ++dt) {
      bf4 o4;
#pragma unroll
      for (int r = 0; r < 4; ++r) o4[r] = f2bf(oaccT[s2][dt][r]);
      *(bf4*)&ob[dt * 16 + 4 * g] = o4;
    }
    float t = lsum_l[s2];
    t += __shfl_xor(t, 16);
    t += __shfl_xor(t, 32);
    if (g == 0) l1[(size_t)split * 16384 + prow] = t;
  }
}

// ---------------------------------------------------------------- combine region1 partials
__global__ __launch_bounds__(256) void comb_k(
    const short* __restrict__ o1, const float* __restrict__ l1,
    short* __restrict__ cat)
{
  int row = blockIdx.x * 32 + (threadIdx.x >> 3);
  int d8 = (threadIdx.x & 7) * 8;
  float l = 0.f;
#pragma unroll
  for (int s = 0; s < 8; ++s) l += l1[(size_t)s * 16384 + row];
  float acc[8] = {};
#pragma unroll
  for (int s = 0; s < 8; ++s) {
    bf8 v = *(const bf8*)&o1[((size_t)s * 16384 + row) * 64 + d8];
#pragma unroll
    for (int j = 0; j < 8; ++j) acc[j] += bf2f(v[j]);
  }
  float rle = 1.f / l;
  bf8 o;
#pragma unroll
  for (int j = 0; j < 8; ++j) o[j] = f2bf(acc[j] * rle);
  int bb = row >> 13, h = (row >> 10) & 7, qr = row & 1023;
  *(bf8*)&cat[(size_t)(bb * 1024 + qr) * 1536 + 512 + h * 64 + d8] = o;
}

// ---------------------------------------------------------------- GEMM (outproj, round-9 verbatim)
__global__ __launch_bounds__(256) void gemmo_k(
    const short* __restrict__ A, const short* __restrict__ wT,
    const float* __restrict__ bias, float* __restrict__ out)
{
  __shared__ __align__(16) short a_lds[2][64 * 40];
  __shared__ __align__(16) short b_lds[2][64 * 40];
  const int tid = threadIdx.x;
  const int w = tid >> 6, lane = tid & 63, g = lane >> 4, lr = lane & 15;
  const int id = blockIdx.x;
  const int m = ((id >> 3) & 3) | ((id & 7) << 2);
  const int n = id >> 5;
  const int m0 = m * 64, n0 = n * 64;
  const int K = 1536;

  f32x4 z = {0.f, 0.f, 0.f, 0.f};
  f32x4 acc[4];
#pragma unroll
  for (int mi = 0; mi < 4; ++mi) acc[mi] = z;

  const int arow = tid >> 2, ac8 = tid & 3;
  const int bcol = tid & 63, bj4 = tid >> 6;
  bf8 ra, rna, rb, rnb;

  auto LOADAB = [&](int kg, bf8& ab, bf8& bb) {
    ab = *(const bf8*)&A[(size_t)(m0 + arow) * K + kg + ac8 * 8];
    bb = *(const bf8*)&wT[(size_t)(n0 + bcol) * K + kg + bj4 * 8];
  };
  auto STAGE = [&](int b, bf8 ab, bf8 bb) {
    *(bf8*)&a_lds[b][arow * 40 + ((ac8 ^ (arow & 3)) << 3)] = ab;
    *(bf8*)&b_lds[b][bcol * 40 + ((bj4 ^ (bcol & 3)) << 3)] = bb;
  };

  const int nit = K >> 5;
  LOADAB(0, ra, rb);
  STAGE(0, ra, rb);
  LOADAB(32, rna, rnb);
  __syncthreads();

  for (int it = 0; it < nit; ++it) {
    if (it + 1 < nit) STAGE((it + 1) & 1, rna, rnb);
    if (it + 2 < nit) LOADAB((it + 2) * 32, rna, rnb);

    const int b = it & 1;
    bf8 afr[4], bfr;
#pragma unroll
    for (int mi = 0; mi < 4; ++mi) {
      int row = mi * 16 + lr;
      afr[mi] = *(const bf8*)&a_lds[b][row * 40 + ((g ^ (row & 3)) << 3)];
    }
    {
      int col = w * 16 + lr;
      bfr = *(const bf8*)&b_lds[b][col * 40 + ((g ^ (col & 3)) << 3)];
    }
#pragma unroll
    for (int mi = 0; mi < 4; ++mi) acc[mi] = mfma16(afr[mi], bfr, acc[mi]);
    __syncthreads();
  }

  {
    int col = n0 + w * 16 + lr;
    float bv = bias[col];
#pragma unroll
    for (int mi = 0; mi < 4; ++mi) {
      int rowb = m0 + mi * 16 + g * 4;
#pragma unroll
      for (int r = 0; r < 4; ++r)
        out[(size_t)(rowb + r) * 512 + col] = acc[mi][r] + bv;
    }
  }
}

// ---------------------------------------------------------------- launch
extern "C" void kernel_launch(void* const* d_in, const int* in_sizes, int n_in,
                              void* d_out, int out_size, void* d_ws, size_t ws_size,
                              hipStream_t stream) {
  const float* x     = (const float*)d_in[0];
  const float* fore  = (const float*)d_in[1];
  const float* post  = (const float*)d_in[2];
  const float* wq    = (const float*)d_in[3];
  const float* bq    = (const float*)d_in[4];
  const float* wkv1  = (const float*)d_in[5];
  const float* bkv1  = (const float*)d_in[6];
  const float* wkv2  = (const float*)d_in[7];
  const float* bkv2  = (const float*)d_in[8];
  const float* wproj = (const float*)d_in[9];
  const float* bproj = (const float*)d_in[10];

  char* ws = (char*)d_ws;
  short* qb     = (short*)ws;                       // 2048*512  bf16 =  2 MB
  short* kv1    = (short*)(ws + (2ull << 20));      // 8192*1024 bf16 = 16 MB
  short* kv2    = (short*)(ws + (18ull << 20));     // 512*1024  bf16 =  1 MB
  short* cat    = (short*)(ws + (19ull << 20));     // 2048*1536 bf16 =  6 MB
  short* o1     = (short*)(ws + (25ull << 20));     // 8*16384*64 bf16 = 16 MB
  float* l1     = (float*)(ws + (41ull << 20));     // 8*16384 f32 = 512 KB
  short* wT     = (short*)(ws + (42ull << 20));     // 512*1536 bf16 = 1.5 MB
  short* xb     = (short*)(ws + (44ull << 20));     // 2048*512 bf16 = 2 MB
  short* fb     = (short*)(ws + (46ull << 20));     // 8192*256 bf16 = 4 MB
  short* pb     = (short*)(ws + (50ull << 20));     // 512*1024 bf16 = 1 MB
  short* wqT    = (short*)(ws + (51ull << 20));     // 512*512 bf16 = 0.5 MB
  short* wkv1T  = (short*)(ws + (52ull << 20));     // 1024*256 bf16 = 0.5 MB
  short* wkv2T  = (short*)(ws + (53ull << 20));     // 1024*1024 bf16 = 2 MB

  cvtw_k<<<1472, 256, 0, stream>>>(x, fore, post, wq, wkv1, wkv2, wproj,
                                   xb, fb, pb, cat, wqT, wkv1T, wkv2T, wT);
  mega1_k<<<1216, 256, 0, stream>>>(xb, fb, pb, wqT, wkv1T, wkv2T,
                                    bq, bkv1, bkv2, qb, kv1, kv2);
  attn_k<<<1152, 256, 0, stream>>>(qb, kv1, kv2, o1, l1, cat);
  comb_k<<<512, 256, 0, stream>>>(o1, l1, cat);
  gemmo_k<<<256, 256, 0, stream>>>(cat, wT, bproj, (float*)d_out);
}